// Round 17
// baseline (444.379 us; speedup 1.0000x reference)
//
#include <hip/hip_runtime.h>
#include <hip/hip_bf16.h>
#include <math.h>

#define HH 192
#define WW 192
#define HW (192*192)

typedef __attribute__((ext_vector_type(8))) short bfrag;   // 8 x bf16 (4 VGPR)
typedef __attribute__((ext_vector_type(4))) float ffrag;   // 4 x f32 acc

__device__ __forceinline__ float bf2f(ushort u){
    union { unsigned int i; float f; } c; c.i = ((unsigned int)u) << 16; return c.f;
}
__device__ __forceinline__ ushort f2bf(float f){
    __hip_bfloat16 h = __float2bfloat16(f);
    return *reinterpret_cast<ushort*>(&h);
}

// ---------------- prep: z=0 NCHW->NHWC bf16 (64ch); z=1 ref_x flip-augment (32ch) ----------------
__global__ __launch_bounds__(256)
void k_prep(const float* __restrict__ x, const float* __restrict__ rx,
            ushort* __restrict__ xbf, ushort* __restrict__ rcbf){
    const int n = blockIdx.y;
    const int tid = threadIdx.x;
    if (blockIdx.z == 0){
        __shared__ ushort sT[256*64];
        const int px0 = blockIdx.x * 256;
        for (int c = 0; c < 64; ++c){
            float v = x[((size_t)(n*64 + c))*HW + px0 + tid];
            int slot = (((c >> 3) ^ (tid & 7)) << 3) + (c & 7);
            sT[tid*64 + slot] = f2bf(v);
        }
        __syncthreads();
        for (int r = 0; r < 8; ++r){
            int u = r*256 + tid;
            int pl = u >> 3, g = u & 7;
            uint4 v = *(const uint4*)&sT[pl*64 + ((g ^ (pl & 7)) << 3)];
            *(uint4*)(xbf + ((size_t)n*HW + px0 + pl)*64 + g*8) = v;
        }
    } else {
        const int px = blockIdx.x*256 + tid;
        const int y = px / WW, xx = px - y*WW;
        ushort v[32];
#pragma unroll
        for (int m = 0; m < 4; ++m){
            int ry = (m & 1) ? (HH-1-y) : y;
            int rxp = (m & 2) ? (WW-1-xx) : xx;
#pragma unroll
            for (int c = 0; c < 3; ++c)
                v[m*3+c] = f2bf(rx[((size_t)(n*3+c))*HW + ry*WW + rxp]);
        }
#pragma unroll
        for (int j = 12; j < 32; ++j) v[j] = 0;
#pragma unroll
        for (int k = 0; k < 4; ++k)
            *(uint4*)(rcbf + ((size_t)n*HW + px)*32 + k*8) = *(uint4*)&v[k*8];
    }
}

// ---------------- all weights -> MFMA A-fragment order, one launch ----------------
__global__ void k_wfrag_all(const float* __restrict__ w0, const float* __restrict__ w1,
                            const float* __restrict__ w2, const float* __restrict__ w3,
                            const float* __restrict__ w4, const float* __restrict__ w5,
                            ushort* __restrict__ f0, ushort* __restrict__ f1,
                            ushort* __restrict__ f2, ushort* __restrict__ f3,
                            ushort* __restrict__ f4, ushort* __restrict__ f5){
    const float* w; ushort* wf; int cin_real, ncb, cout_real, mt;
    switch (blockIdx.y){
        case 0: w=w0; wf=f0; cin_real=12;  ncb=1; cout_real=64; mt=4; break;
        case 1: w=w1; wf=f1; cin_real=128; ncb=4; cout_real=64; mt=4; break;
        case 2: w=w2; wf=f2; cin_real=64;  ncb=2; cout_real=64; mt=4; break;
        case 3: w=w3; wf=f3; cin_real=64;  ncb=2; cout_real=18; mt=2; break;
        case 4: w=w4; wf=f4; cin_real=64;  ncb=2; cout_real=64; mt=4; break;
        default:w=w5; wf=f5; cin_real=64;  ncb=2; cout_real=3;  mt=1; break;
    }
    int idx = blockIdx.x*256 + threadIdx.x;
    int total = ncb*9*mt*512;
    if (idx >= total) return;
    int e = idx & 7;
    int lane = (idx >> 3) & 63;
    int rest = idx >> 9;
    int mtl = rest % mt;
    int tap = (rest / mt) % 9;
    int cb  = rest / (mt*9);
    int cout = mtl*16 + (lane & 15);
    int cin  = cb*32 + ((lane >> 4) << 3) + e;
    float v = 0.f;
    if (cout < cout_real && cin < cin_real)
        v = w[((size_t)cout*cin_real + cin)*9 + tap];
    wf[idx] = f2bf(v);
}

// ---------------- implicit-GEMM 3x3 conv body (round-13 proven version) ----------------
// grid dim3(12,12,8): bx,by tile, z = image. 256 thr = 4 waves; 16x16 px x MT*16 couts.
template<int NCB, int MT, bool SCALE, bool CONCAT, bool RELU, int OM, bool GAPP>
__device__ __forceinline__
void conv_body(const ushort* __restrict__ in0, const ushort* __restrict__ in1,
               const ushort* __restrict__ wf, const float* __restrict__ bias,
               const float* __restrict__ scale,
               ushort* __restrict__ obf, float* __restrict__ of0, float* __restrict__ of1,
               float* __restrict__ part, int cout_real)
{
    __shared__ ushort sXt[18*18*32];
    __shared__ float sG[4][4][16];
    const int tid = threadIdx.x;
    const int lane = tid & 63;
    const int wv = tid >> 6;
    const int n = blockIdx.z;
    const int ty0 = blockIdx.y*16, tx0 = blockIdx.x*16;
    const int lx = lane & 15;
    const int lg = lane >> 4;

    ffrag acc[MT][4];
#pragma unroll
    for (int mt = 0; mt < MT; ++mt)
#pragma unroll
        for (int q = 0; q < 4; ++q) acc[mt][q] = (ffrag){0.f,0.f,0.f,0.f};

    for (int cb = 0; cb < NCB; ++cb){
        __syncthreads();
        for (int u = tid; u < 1296; u += 256){
            int yy = u / 72; int rr = u - yy*72; int xx = rr >> 2; int g = rr & 3;
            int gy = ty0 - 1 + yy, gx = tx0 - 1 + xx;
            uint4 val = make_uint4(0,0,0,0);
            if (gy >= 0 && gy < HH && gx >= 0 && gx < WW){
                const ushort* src; int ch; int stride;
                if constexpr (CONCAT){
                    src = (cb < 2) ? in0 : in1;
                    ch = (cb & 1)*32 + g*8;
                    stride = 64;
                } else {
                    src = in0; ch = cb*32 + g*8; stride = NCB*32;
                }
                val = *(const uint4*)(src + ((size_t)n*HW + gy*WW + gx)*stride + ch);
                if constexpr (SCALE){
                    ushort* e = (ushort*)&val;
                    int cb8 = cb*32 + g*8;
#pragma unroll
                    for (int j = 0; j < 8; ++j)
                        e[j] = f2bf(bf2f(e[j]) * scale[n*64 + cb8 + j]);
                }
            }
            *(uint4*)&sXt[((yy*18 + xx)*4 + (g ^ ((xx >> 1) & 3)))*8] = val;
        }
        __syncthreads();

        const bfrag* wbase = (const bfrag*)wf + (size_t)cb*9*MT*64 + lane;
        bfrag a[MT];
#pragma unroll
        for (int mt = 0; mt < MT; ++mt) a[mt] = wbase[mt*64];

#pragma unroll
        for (int tap = 0; tap < 9; ++tap){
            const int ky = tap / 3, kx = tap % 3;
            bfrag an[MT];
            if (tap < 8){
#pragma unroll
                for (int mt = 0; mt < MT; ++mt) an[mt] = wbase[(tap+1)*MT*64 + mt*64];
            }
#pragma unroll
            for (int q = 0; q < 4; ++q){
                const int yl = wv*4 + q + ky;
                const int xl = lx + kx;
                bfrag b = *(const bfrag*)&sXt[((yl*18 + xl)*4 + (lg ^ ((xl >> 1) & 3)))*8];
#pragma unroll
                for (int mt = 0; mt < MT; ++mt)
                    acc[mt][q] = __builtin_amdgcn_mfma_f32_16x16x32_bf16(a[mt], b, acc[mt][q], 0, 0, 0);
            }
            if (tap < 8){
#pragma unroll
                for (int mt = 0; mt < MT; ++mt) a[mt] = an[mt];
            }
        }
    }
    const int gx = tx0 + lx;
    float psum[MT][4];
    if constexpr (GAPP){
#pragma unroll
        for (int mt = 0; mt < MT; ++mt)
#pragma unroll
            for (int j = 0; j < 4; ++j) psum[mt][j] = 0.f;
    }
#pragma unroll
    for (int mt = 0; mt < MT; ++mt){
        const int co0 = mt*16 + lg*4;
#pragma unroll
        for (int q = 0; q < 4; ++q){
            const int gy = ty0 + wv*4 + q;
            float r[4];
#pragma unroll
            for (int j = 0; j < 4; ++j){
                float bv = (co0 + j < cout_real) ? bias[co0 + j] : 0.f;
                float v = acc[mt][q][j] + bv;
                if (RELU) v = fmaxf(v, 0.f);
                r[j] = v;
            }
            if constexpr (GAPP){
#pragma unroll
                for (int j = 0; j < 4; ++j) psum[mt][j] += r[j];
            }
            if constexpr (OM & 1){
                ushort pk[4];
#pragma unroll
                for (int j = 0; j < 4; ++j) pk[j] = f2bf(r[j]);
                *(uint2*)(obf + ((size_t)n*HW + gy*WW + gx)*64 + co0) = *(uint2*)pk;
            }
            if constexpr (OM & 2){
#pragma unroll
                for (int j = 0; j < 4; ++j){
                    int c = co0 + j;
                    if (c < cout_real){
                        size_t o = ((size_t)(n*cout_real + c))*HW + (size_t)gy*WW + gx;
                        of0[o] = r[j];
                        if (of1) of1[o] = r[j];
                    }
                }
            }
        }
    }
    if constexpr (GAPP){
#pragma unroll
        for (int mt = 0; mt < MT; ++mt)
#pragma unroll
            for (int j = 0; j < 4; ++j){
                float v = psum[mt][j];
#pragma unroll
                for (int d = 1; d < 16; d <<= 1) v += __shfl_xor(v, d, 64);
                if (lx == 0) sG[wv][lg][mt*4 + j] = v;
            }
        __syncthreads();
        if (tid < 64){
            int mt = tid >> 4, lgc = (tid >> 2) & 3, j = tid & 3;
            float s = sG[0][lgc][mt*4+j] + sG[1][lgc][mt*4+j]
                    + sG[2][lgc][mt*4+j] + sG[3][lgc][mt*4+j];
            part[(((size_t)n*144) + blockIdx.y*12 + blockIdx.x)*64 + tid] = s;
        }
    }
}

// -------- uniquely-named conv kernels; launch_bounds(256,4) caps VGPR at 128 -> 4+ blocks/CU --------
__global__ __launch_bounds__(256, 4)
void kc_ref(const ushort* __restrict__ in0, const ushort* __restrict__ wf,
            const float* __restrict__ bias, ushort* __restrict__ obf){
    conv_body<1,4,false,false,true,1,false>(in0, nullptr, wf, bias, nullptr, obf, nullptr, nullptr, nullptr, 64);
}
__global__ __launch_bounds__(256, 4)
void kc_off1(const ushort* __restrict__ in0, const ushort* __restrict__ in1,
             const ushort* __restrict__ wf, const float* __restrict__ bias,
             ushort* __restrict__ obf, float* __restrict__ part){
    conv_body<4,4,false,true,true,1,true>(in0, in1, wf, bias, nullptr, obf, nullptr, nullptr, part, 64);
}
__global__ __launch_bounds__(256, 4)
void kc_off2(const ushort* __restrict__ in0, const ushort* __restrict__ wf,
             const float* __restrict__ bias, const float* __restrict__ scale,
             ushort* __restrict__ obf, float* __restrict__ part){
    conv_body<2,4,true,false,true,1,true>(in0, nullptr, wf, bias, scale, obf, nullptr, nullptr, part, 64);
}
__global__ __launch_bounds__(256, 4)
void kc_off3(const ushort* __restrict__ in0, const ushort* __restrict__ wf,
             const float* __restrict__ bias, const float* __restrict__ scale,
             float* __restrict__ of0, float* __restrict__ of1){
    conv_body<2,2,true,false,false,2,false>(in0, nullptr, wf, bias, scale, nullptr, of0, of1, nullptr, 18);
}
__global__ __launch_bounds__(256, 4)
void kc_rgb(const ushort* __restrict__ in0, const ushort* __restrict__ wf,
            const float* __restrict__ bias, float* __restrict__ of0){
    conv_body<2,1,false,false,false,2,false>(in0, nullptr, wf, bias, nullptr, nullptr, of0, nullptr, nullptr, 3);
}

// ---------------- channel-attention FC ----------------
__global__ void k_cafc(const float* __restrict__ part, const float* __restrict__ w1,
                       const float* __restrict__ b1, const float* __restrict__ w2,
                       const float* __restrict__ b2, float* __restrict__ s)
{
    int n = blockIdx.x;
    int c = threadIdx.x;  // 64
    __shared__ float y[64], z[4];
    float acc = 0.f;
    for (int b = 0; b < 144; ++b) acc += part[((size_t)n*144 + b)*64 + c];
    y[c] = acc * (1.f/(float)HW);
    __syncthreads();
    if (c < 4){
        float a = b1[c];
        for (int i = 0; i < 64; ++i) a = fmaf(w1[c*64+i], y[i], a);
        z[c] = fmaxf(a, 0.f);
    }
    __syncthreads();
    float a = b2[c];
#pragma unroll
    for (int q = 0; q < 4; ++q) a = fmaf(w2[c*4+q], z[q], a);
    s[n*64+c] = 1.f/(1.f+expf(-a));
}

// ---------------- deformable conv: 8x16 tile, dbuf LDS, pixel-grouped gather -> MFMA ----------------
// Round-13 proven structure: 2304 blocks, dbuf 2x16KB, one barrier per tap, acc[4][2].
__global__ __launch_bounds__(256, 2)
void k_dcnm(const ushort* __restrict__ xbf, const float* __restrict__ off,
            const ushort* __restrict__ wf, const float* __restrict__ bias,
            float* __restrict__ xo, ushort* __restrict__ xobf)
{
    __shared__ ushort sS[2][128*64];   // [buf][pixel*64 + slot*8 + e], slot = slice ^ (p&7); 2x16KB
    const int tid = threadIdx.x;
    const int lane = tid & 63;
    const int wv = tid >> 6;
    const int n = blockIdx.z;
    const int ty0 = blockIdx.y*8, tx0 = blockIdx.x*16;
    const int lx = lane & 15;
    const int lg = lane >> 4;
    const int gx_out = tx0 + lx;
    const int gp = tid >> 2;
    const int gg = tid & 3;

    const ushort* xn = xbf + (size_t)n*HW*64;
    const float* offn = off + (size_t)n*18*HW;

    ffrag acc[4][2];
#pragma unroll
    for (int mt = 0; mt < 4; ++mt)
#pragma unroll
        for (int q = 0; q < 2; ++q) acc[mt][q] = (ffrag){0.f,0.f,0.f,0.f};

    int buf = 0;
    for (int tap = 0; tap < 9; ++tap){
        const int ti = tap/3, tj = tap%3;
#pragma unroll
        for (int pass = 0; pass < 2; ++pass){
            const int p = pass*64 + gp;
            const int py_ = ty0 + (p >> 4), px_ = tx0 + (p & 15);
            float dy = offn[(size_t)(2*tap)*HW + py_*WW + px_];
            float dx = offn[(size_t)(2*tap+1)*HW + py_*WW + px_];
            float sy = (float)(py_ + ti - 1) + dy;
            float sx = (float)(px_ + tj - 1) + dx;
            float y0f = floorf(sy), x0f = floorf(sx);
            float wy1 = sy - y0f, wx1 = sx - x0f;
            float wy0 = 1.f - wy1, wx0 = 1.f - wx1;
            int y0 = (int)y0f, x0 = (int)x0f;
            int y1 = y0+1, x1 = x0+1;
            float vy0 = (y0 >= 0 && y0 < HH) ? 1.f : 0.f;
            float vy1 = (y1 >= 0 && y1 < HH) ? 1.f : 0.f;
            float vx0 = (x0 >= 0 && x0 < WW) ? 1.f : 0.f;
            float vx1 = (x1 >= 0 && x1 < WW) ? 1.f : 0.f;
            float w00 = wy0*wx0*vy0*vx0, w01 = wy0*wx1*vy0*vx1;
            float w10 = wy1*wx0*vy1*vx0, w11 = wy1*wx1*vy1*vx1;
            int yc0 = min(max(y0,0),HH-1), yc1 = min(max(y1,0),HH-1);
            int xc0 = min(max(x0,0),WW-1), xc1 = min(max(x1,0),WW-1);
            int b00 = (yc0*WW + xc0)*64, b01 = (yc0*WW + xc1)*64;
            int b10 = (yc1*WW + xc0)*64, b11 = (yc1*WW + xc1)*64;
#pragma unroll
            for (int cb = 0; cb < 2; ++cb){
                const int ch = cb*32 + gg*8;
                uint4 c00 = *(const uint4*)(xn + b00 + ch);
                uint4 c01 = *(const uint4*)(xn + b01 + ch);
                uint4 c10 = *(const uint4*)(xn + b10 + ch);
                uint4 c11 = *(const uint4*)(xn + b11 + ch);
                const ushort* e00 = (const ushort*)&c00;
                const ushort* e01 = (const ushort*)&c01;
                const ushort* e10 = (const ushort*)&c10;
                const ushort* e11 = (const ushort*)&c11;
                ushort pk[8];
#pragma unroll
                for (int j = 0; j < 8; ++j){
                    float s = bf2f(e00[j])*w00 + bf2f(e01[j])*w01
                            + bf2f(e10[j])*w10 + bf2f(e11[j])*w11;
                    pk[j] = f2bf(s);
                }
                const int sl = (cb*4 + gg) ^ (p & 7);
                *(uint4*)&sS[buf][p*64 + sl*8] = *(uint4*)pk;
            }
        }
        __syncthreads();
#pragma unroll
        for (int cb = 0; cb < 2; ++cb){
            const bfrag* wbase = (const bfrag*)wf + ((size_t)(cb*9 + tap)*4)*64 + lane;
            bfrag a[4];
#pragma unroll
            for (int mt = 0; mt < 4; ++mt) a[mt] = wbase[mt*64];
#pragma unroll
            for (int q = 0; q < 2; ++q){
                const int p = (wv*2 + q)*16 + lx;
                const int sl = (cb*4 + lg) ^ (p & 7);
                bfrag b = *(const bfrag*)&sS[buf][p*64 + sl*8];
#pragma unroll
                for (int mt = 0; mt < 4; ++mt)
                    acc[mt][q] = __builtin_amdgcn_mfma_f32_16x16x32_bf16(a[mt], b, acc[mt][q], 0, 0, 0);
            }
        }
        buf ^= 1;
    }
#pragma unroll
    for (int mt = 0; mt < 4; ++mt){
        const int co0 = mt*16 + lg*4;
#pragma unroll
        for (int q = 0; q < 2; ++q){
            const int gy = ty0 + wv*2 + q;
            float r[4];
            ushort pk[4];
#pragma unroll
            for (int j = 0; j < 4; ++j){
                r[j] = fmaxf(acc[mt][q][j] + bias[co0+j], 0.f);
                pk[j] = f2bf(r[j]);
            }
#pragma unroll
            for (int j = 0; j < 4; ++j)
                xo[((size_t)(n*64 + co0 + j))*HW + (size_t)gy*WW + gx_out] = r[j];
            *(uint2*)(xobf + ((size_t)n*HW + gy*WW + gx_out)*64 + co0) = *(uint2*)pk;
        }
    }
}

extern "C" void kernel_launch(void* const* d_in, const int* in_sizes, int n_in,
                              void* d_out, int out_size, void* d_ws, size_t ws_size,
                              hipStream_t stream)
{
    const float* x      = (const float*)d_in[0];
    const float* ref_x  = (const float*)d_in[1];
    const float* ref_w  = (const float*)d_in[2];
    const float* ref_b  = (const float*)d_in[3];
    const float* off_w1 = (const float*)d_in[4];
    const float* off_b1 = (const float*)d_in[5];
    const float* ca1_w1 = (const float*)d_in[6];
    const float* ca1_b1 = (const float*)d_in[7];
    const float* ca1_w2 = (const float*)d_in[8];
    const float* ca1_b2 = (const float*)d_in[9];
    const float* off_w2 = (const float*)d_in[10];
    const float* off_b2 = (const float*)d_in[11];
    const float* ca2_w1 = (const float*)d_in[12];
    const float* ca2_b1 = (const float*)d_in[13];
    const float* ca2_w2 = (const float*)d_in[14];
    const float* ca2_b2 = (const float*)d_in[15];
    const float* off_w3 = (const float*)d_in[16];
    const float* off_b3 = (const float*)d_in[17];
    const float* dcn_w  = (const float*)d_in[18];
    const float* dcn_b  = (const float*)d_in[19];
    const float* rgb_w  = (const float*)d_in[20];
    const float* rgb_b  = (const float*)d_in[21];

    float* out = (float*)d_out;
    const size_t XO  = (size_t)8 * 64 * HW;
    const size_t RGB = (size_t)8 * 3 * HW;
    const size_t OFF = (size_t)8 * 18 * HW;
    float* xo_out   = out;
    float* rgb_out  = out + XO;
    float* mask_out = out + XO + RGB;
    float* off_out  = out + XO + RGB + OFF;

    const size_t NPX = (size_t)8 * HW;
    ushort* ws16  = (ushort*)d_ws;
    ushort* x_bf  = ws16;                       // NPX*64
    ushort* bufP  = x_bf + NPX*64;              // ref_f, later t2
    ushort* bufQ  = bufP + NPX*64;              // t1, later xo_bf
    ushort* rc_bf = bufQ + NPX*64;              // NPX*32
    ushort* wf_ref = rc_bf + NPX*32;            // 18432
    ushort* wf_1   = wf_ref + 18432;            // 73728
    ushort* wf_2   = wf_1 + 73728;              // 36864
    ushort* wf_3   = wf_2 + 36864;              // 18432
    ushort* wf_d   = wf_3 + 18432;              // 36864
    ushort* wf_r   = wf_d + 36864;              // 9216
    float*  part1  = (float*)(wf_r + 9216);     // 8*144*64
    float*  part2  = part1 + 73728;
    float*  s1     = part2 + 73728;
    float*  s2     = s1 + 512;

    dim3 pg(144, 8, 2), cg(12, 12, 8), dg(12, 24, 8);

    k_prep<<<pg, 256, 0, stream>>>(x, ref_x, x_bf, rc_bf);
    k_wfrag_all<<<dim3(288, 6), 256, 0, stream>>>(
        ref_w, off_w1, off_w2, off_w3, dcn_w, rgb_w,
        wf_ref, wf_1, wf_2, wf_3, wf_d, wf_r);

    // ref: 32ch(12 real) -> 64, relu, bf16 out
    kc_ref<<<cg, 256, 0, stream>>>(rc_bf, wf_ref, ref_b, bufP);
    // off1: concat(x, ref_f) 128 -> 64, relu, bf16 out + GAP partials
    kc_off1<<<cg, 256, 0, stream>>>(x_bf, bufP, wf_1, off_b1, bufQ, part1);
    k_cafc<<<8, 64, 0, stream>>>(part1, ca1_w1, ca1_b1, ca1_w2, ca1_b2, s1);
    // off2: (t1*s1) 64 -> 64, relu, bf16 out + GAP partials
    kc_off2<<<cg, 256, 0, stream>>>(bufQ, wf_2, off_b2, s1, bufP, part2);
    k_cafc<<<8, 64, 0, stream>>>(part2, ca2_w1, ca2_b1, ca2_w2, ca2_b2, s2);
    // off3: (t2*s2) 64 -> 18, f32 NCHW dual (offset + mask)
    kc_off3<<<cg, 256, 0, stream>>>(bufP, wf_3, off_b3, s2, off_out, mask_out);
    // deformable conv -> xo (f32 NCHW) + xo_bf (NHWC)
    k_dcnm<<<dg, 256, 0, stream>>>(x_bf, off_out, wf_d, dcn_b, xo_out, bufQ);
    // rgb: xo 64 -> 3, f32 NCHW
    kc_rgb<<<cg, 256, 0, stream>>>(bufQ, wf_r, rgb_b, rgb_out);
}

// Round 18
// 320.131 us; speedup vs baseline: 1.3881x; 1.3881x over previous
//
#include <hip/hip_runtime.h>
#include <hip/hip_bf16.h>
#include <math.h>

#define HH 192
#define WW 192
#define HW (192*192)

typedef __attribute__((ext_vector_type(8))) short bfrag;   // 8 x bf16 (4 VGPR)
typedef __attribute__((ext_vector_type(4))) float ffrag;   // 4 x f32 acc

__device__ __forceinline__ float bf2f(ushort u){
    union { unsigned int i; float f; } c; c.i = ((unsigned int)u) << 16; return c.f;
}
__device__ __forceinline__ ushort f2bf(float f){
    __hip_bfloat16 h = __float2bfloat16(f);
    return *reinterpret_cast<ushort*>(&h);
}

// ---------------- prep: z=0 NCHW->NHWC bf16 (64ch); z=1 ref_x flip-augment (32ch) ----------------
__global__ __launch_bounds__(256)
void k_prep(const float* __restrict__ x, const float* __restrict__ rx,
            ushort* __restrict__ xbf, ushort* __restrict__ rcbf){
    const int n = blockIdx.y;
    const int tid = threadIdx.x;
    if (blockIdx.z == 0){
        __shared__ ushort sT[256*64];
        const int px0 = blockIdx.x * 256;
        for (int c = 0; c < 64; ++c){
            float v = x[((size_t)(n*64 + c))*HW + px0 + tid];
            int slot = (((c >> 3) ^ (tid & 7)) << 3) + (c & 7);
            sT[tid*64 + slot] = f2bf(v);
        }
        __syncthreads();
        for (int r = 0; r < 8; ++r){
            int u = r*256 + tid;
            int pl = u >> 3, g = u & 7;
            uint4 v = *(const uint4*)&sT[pl*64 + ((g ^ (pl & 7)) << 3)];
            *(uint4*)(xbf + ((size_t)n*HW + px0 + pl)*64 + g*8) = v;
        }
    } else {
        const int px = blockIdx.x*256 + tid;
        const int y = px / WW, xx = px - y*WW;
        ushort v[32];
#pragma unroll
        for (int m = 0; m < 4; ++m){
            int ry = (m & 1) ? (HH-1-y) : y;
            int rxp = (m & 2) ? (WW-1-xx) : xx;
#pragma unroll
            for (int c = 0; c < 3; ++c)
                v[m*3+c] = f2bf(rx[((size_t)(n*3+c))*HW + ry*WW + rxp]);
        }
#pragma unroll
        for (int j = 12; j < 32; ++j) v[j] = 0;
#pragma unroll
        for (int k = 0; k < 4; ++k)
            *(uint4*)(rcbf + ((size_t)n*HW + px)*32 + k*8) = *(uint4*)&v[k*8];
    }
}

// ---------------- all weights -> MFMA A-fragment order, one launch ----------------
__global__ void k_wfrag_all(const float* __restrict__ w0, const float* __restrict__ w1,
                            const float* __restrict__ w2, const float* __restrict__ w3,
                            const float* __restrict__ w4, const float* __restrict__ w5,
                            ushort* __restrict__ f0, ushort* __restrict__ f1,
                            ushort* __restrict__ f2, ushort* __restrict__ f3,
                            ushort* __restrict__ f4, ushort* __restrict__ f5){
    const float* w; ushort* wf; int cin_real, ncb, cout_real, mt;
    switch (blockIdx.y){
        case 0: w=w0; wf=f0; cin_real=12;  ncb=1; cout_real=64; mt=4; break;
        case 1: w=w1; wf=f1; cin_real=128; ncb=4; cout_real=64; mt=4; break;
        case 2: w=w2; wf=f2; cin_real=64;  ncb=2; cout_real=64; mt=4; break;
        case 3: w=w3; wf=f3; cin_real=64;  ncb=2; cout_real=18; mt=2; break;
        case 4: w=w4; wf=f4; cin_real=64;  ncb=2; cout_real=64; mt=4; break;
        default:w=w5; wf=f5; cin_real=64;  ncb=2; cout_real=3;  mt=1; break;
    }
    int idx = blockIdx.x*256 + threadIdx.x;
    int total = ncb*9*mt*512;
    if (idx >= total) return;
    int e = idx & 7;
    int lane = (idx >> 3) & 63;
    int rest = idx >> 9;
    int mtl = rest % mt;
    int tap = (rest / mt) % 9;
    int cb  = rest / (mt*9);
    int cout = mtl*16 + (lane & 15);
    int cin  = cb*32 + ((lane >> 4) << 3) + e;
    float v = 0.f;
    if (cout < cout_real && cin < cin_real)
        v = w[((size_t)cout*cin_real + cin)*9 + tap];
    wf[idx] = f2bf(v);
}

// ---------------- implicit-GEMM 3x3 conv body ----------------
// grid dim3(12,12,8): bx,by tile, z = image. 256 thr = 4 waves; 16x16 px x MT*16 couts.
// OM&1 epilogue: stage output tile in LDS (two 8-row passes, 16B-granule XOR swizzle),
// stream out as full 128B/pixel lines -> no write-allocate FETCH inflation.
template<int NCB, int MT, bool SCALE, bool CONCAT, bool RELU, int OM, bool GAPP>
__device__ __forceinline__
void conv_body(const ushort* __restrict__ in0, const ushort* __restrict__ in1,
               const ushort* __restrict__ wf, const float* __restrict__ bias,
               const float* __restrict__ scale,
               ushort* __restrict__ obf, float* __restrict__ of0, float* __restrict__ of1,
               float* __restrict__ part, int cout_real)
{
    __shared__ ushort sXt[18*18*32];
    __shared__ float sG[4][4][16];
    __shared__ ushort sOut[(OM & 1) ? 8*16*64 : 1];   // 16KB half-tile out-stage
    const int tid = threadIdx.x;
    const int lane = tid & 63;
    const int wv = tid >> 6;
    const int n = blockIdx.z;
    const int ty0 = blockIdx.y*16, tx0 = blockIdx.x*16;
    const int lx = lane & 15;
    const int lg = lane >> 4;

    ffrag acc[MT][4];
#pragma unroll
    for (int mt = 0; mt < MT; ++mt)
#pragma unroll
        for (int q = 0; q < 4; ++q) acc[mt][q] = (ffrag){0.f,0.f,0.f,0.f};

    for (int cb = 0; cb < NCB; ++cb){
        __syncthreads();
        for (int u = tid; u < 1296; u += 256){
            int yy = u / 72; int rr = u - yy*72; int xx = rr >> 2; int g = rr & 3;
            int gy = ty0 - 1 + yy, gx = tx0 - 1 + xx;
            uint4 val = make_uint4(0,0,0,0);
            if (gy >= 0 && gy < HH && gx >= 0 && gx < WW){
                const ushort* src; int ch; int stride;
                if constexpr (CONCAT){
                    src = (cb < 2) ? in0 : in1;
                    ch = (cb & 1)*32 + g*8;
                    stride = 64;
                } else {
                    src = in0; ch = cb*32 + g*8; stride = NCB*32;
                }
                val = *(const uint4*)(src + ((size_t)n*HW + gy*WW + gx)*stride + ch);
                if constexpr (SCALE){
                    ushort* e = (ushort*)&val;
                    int cb8 = cb*32 + g*8;
#pragma unroll
                    for (int j = 0; j < 8; ++j)
                        e[j] = f2bf(bf2f(e[j]) * scale[n*64 + cb8 + j]);
                }
            }
            *(uint4*)&sXt[((yy*18 + xx)*4 + (g ^ ((xx >> 1) & 3)))*8] = val;
        }
        __syncthreads();

        const bfrag* wbase = (const bfrag*)wf + (size_t)cb*9*MT*64 + lane;
        bfrag a[MT];
#pragma unroll
        for (int mt = 0; mt < MT; ++mt) a[mt] = wbase[mt*64];

#pragma unroll
        for (int tap = 0; tap < 9; ++tap){
            const int ky = tap / 3, kx = tap % 3;
            bfrag an[MT];
            if (tap < 8){
#pragma unroll
                for (int mt = 0; mt < MT; ++mt) an[mt] = wbase[(tap+1)*MT*64 + mt*64];
            }
#pragma unroll
            for (int q = 0; q < 4; ++q){
                const int yl = wv*4 + q + ky;
                const int xl = lx + kx;
                bfrag b = *(const bfrag*)&sXt[((yl*18 + xl)*4 + (lg ^ ((xl >> 1) & 3)))*8];
#pragma unroll
                for (int mt = 0; mt < MT; ++mt)
                    acc[mt][q] = __builtin_amdgcn_mfma_f32_16x16x32_bf16(a[mt], b, acc[mt][q], 0, 0, 0);
            }
            if (tap < 8){
#pragma unroll
                for (int mt = 0; mt < MT; ++mt) a[mt] = an[mt];
            }
        }
    }
    const int gx = tx0 + lx;
    float psum[MT][4];
    if constexpr (GAPP){
#pragma unroll
        for (int mt = 0; mt < MT; ++mt)
#pragma unroll
            for (int j = 0; j < 4; ++j) psum[mt][j] = 0.f;
    }

    if constexpr (OM & 1){
        // two half-tile passes: waves 0,1 own rows 0..7 (pass 0); waves 2,3 rows 8..15 (pass 1)
#pragma unroll
        for (int pass = 0; pass < 2; ++pass){
            if ((wv >> 1) == pass){
#pragma unroll
                for (int mt = 0; mt < MT; ++mt){
                    const int co0 = mt*16 + lg*4;
                    const int t = mt*2 + (lg >> 1);   // 16B granule index (ch/8)
                    const int h = lg & 1;             // 8B half within granule
#pragma unroll
                    for (int q = 0; q < 4; ++q){
                        const int py_loc = (wv*4 + q) & 7;
                        float r[4];
                        ushort pk[4];
#pragma unroll
                        for (int j = 0; j < 4; ++j){
                            float bv = (co0 + j < cout_real) ? bias[co0 + j] : 0.f;
                            float v = acc[mt][q][j] + bv;
                            if (RELU) v = fmaxf(v, 0.f);
                            r[j] = v;
                            pk[j] = f2bf(v);
                        }
                        if constexpr (GAPP){
#pragma unroll
                            for (int j = 0; j < 4; ++j) psum[mt][j] += r[j];
                        }
                        *(uint2*)&sOut[(py_loc*16 + lx)*64 + ((t ^ (lx & 7)) << 3) + h*4] = *(uint2*)pk;
                    }
                }
            }
            __syncthreads();
            // stream half tile: 1024 x uint4 (full 128B per pixel -> full-sector writes)
#pragma unroll
            for (int it = 0; it < 4; ++it){
                int u = it*256 + tid;
                int p = u >> 3, t = u & 7;
                int py = p >> 4, px = p & 15;
                uint4 v = *(const uint4*)&sOut[(py*16 + px)*64 + ((t ^ (px & 7)) << 3)];
                *(uint4*)(obf + ((size_t)n*HW + (size_t)(ty0 + pass*8 + py)*WW + tx0 + px)*64 + t*8) = v;
            }
            __syncthreads();
        }
    } else {
#pragma unroll
        for (int mt = 0; mt < MT; ++mt){
            const int co0 = mt*16 + lg*4;
#pragma unroll
            for (int q = 0; q < 4; ++q){
                const int gy = ty0 + wv*4 + q;
                float r[4];
#pragma unroll
                for (int j = 0; j < 4; ++j){
                    float bv = (co0 + j < cout_real) ? bias[co0 + j] : 0.f;
                    float v = acc[mt][q][j] + bv;
                    if (RELU) v = fmaxf(v, 0.f);
                    r[j] = v;
                }
                if constexpr (GAPP){
#pragma unroll
                    for (int j = 0; j < 4; ++j) psum[mt][j] += r[j];
                }
#pragma unroll
                for (int j = 0; j < 4; ++j){
                    int c = co0 + j;
                    if (c < cout_real){
                        size_t o = ((size_t)(n*cout_real + c))*HW + (size_t)gy*WW + gx;
                        of0[o] = r[j];
                        if (of1) of1[o] = r[j];
                    }
                }
            }
        }
    }

    if constexpr (GAPP){
#pragma unroll
        for (int mt = 0; mt < MT; ++mt)
#pragma unroll
            for (int j = 0; j < 4; ++j){
                float v = psum[mt][j];
#pragma unroll
                for (int d = 1; d < 16; d <<= 1) v += __shfl_xor(v, d, 64);
                if (lx == 0) sG[wv][lg][mt*4 + j] = v;
            }
        __syncthreads();
        if (tid < 64){
            int mt = tid >> 4, lgc = (tid >> 2) & 3, j = tid & 3;
            float s = sG[0][lgc][mt*4+j] + sG[1][lgc][mt*4+j]
                    + sG[2][lgc][mt*4+j] + sG[3][lgc][mt*4+j];
            part[(((size_t)n*144) + blockIdx.y*12 + blockIdx.x)*64 + tid] = s;
        }
    }
}

// -------- uniquely-named conv kernels (green (256,2) bounds) --------
__global__ __launch_bounds__(256, 2)
void kc_ref(const ushort* __restrict__ in0, const ushort* __restrict__ wf,
            const float* __restrict__ bias, ushort* __restrict__ obf){
    conv_body<1,4,false,false,true,1,false>(in0, nullptr, wf, bias, nullptr, obf, nullptr, nullptr, nullptr, 64);
}
__global__ __launch_bounds__(256, 2)
void kc_off1(const ushort* __restrict__ in0, const ushort* __restrict__ in1,
             const ushort* __restrict__ wf, const float* __restrict__ bias,
             ushort* __restrict__ obf, float* __restrict__ part){
    conv_body<4,4,false,true,true,1,true>(in0, in1, wf, bias, nullptr, obf, nullptr, nullptr, part, 64);
}
__global__ __launch_bounds__(256, 2)
void kc_off2(const ushort* __restrict__ in0, const ushort* __restrict__ wf,
             const float* __restrict__ bias, const float* __restrict__ scale,
             ushort* __restrict__ obf, float* __restrict__ part){
    conv_body<2,4,true,false,true,1,true>(in0, nullptr, wf, bias, scale, obf, nullptr, nullptr, part, 64);
}
__global__ __launch_bounds__(256, 2)
void kc_off3(const ushort* __restrict__ in0, const ushort* __restrict__ wf,
             const float* __restrict__ bias, const float* __restrict__ scale,
             float* __restrict__ of0, float* __restrict__ of1){
    conv_body<2,2,true,false,false,2,false>(in0, nullptr, wf, bias, scale, nullptr, of0, of1, nullptr, 18);
}
__global__ __launch_bounds__(256, 2)
void kc_rgb(const ushort* __restrict__ in0, const ushort* __restrict__ wf,
            const float* __restrict__ bias, float* __restrict__ of0){
    conv_body<2,1,false,false,false,2,false>(in0, nullptr, wf, bias, nullptr, nullptr, of0, nullptr, nullptr, 3);
}

// ---------------- channel-attention FC ----------------
__global__ void k_cafc(const float* __restrict__ part, const float* __restrict__ w1,
                       const float* __restrict__ b1, const float* __restrict__ w2,
                       const float* __restrict__ b2, float* __restrict__ s)
{
    int n = blockIdx.x;
    int c = threadIdx.x;  // 64
    __shared__ float y[64], z[4];
    float acc = 0.f;
    for (int b = 0; b < 144; ++b) acc += part[((size_t)n*144 + b)*64 + c];
    y[c] = acc * (1.f/(float)HW);
    __syncthreads();
    if (c < 4){
        float a = b1[c];
        for (int i = 0; i < 64; ++i) a = fmaf(w1[c*64+i], y[i], a);
        z[c] = fmaxf(a, 0.f);
    }
    __syncthreads();
    float a = b2[c];
#pragma unroll
    for (int q = 0; q < 4; ++q) a = fmaf(w2[c*4+q], z[q], a);
    s[n*64+c] = 1.f/(1.f+expf(-a));
}

// ---------------- deformable conv: 8x16 tile, dbuf LDS, pixel-grouped gather -> MFMA ----------------
// Round-13 proven structure: 2304 blocks, dbuf 2x16KB, one barrier per tap, acc[4][2].
__global__ __launch_bounds__(256, 2)
void k_dcnm(const ushort* __restrict__ xbf, const float* __restrict__ off,
            const ushort* __restrict__ wf, const float* __restrict__ bias,
            float* __restrict__ xo, ushort* __restrict__ xobf)
{
    __shared__ ushort sS[2][128*64];   // [buf][pixel*64 + slot*8 + e], slot = slice ^ (p&7); 2x16KB
    const int tid = threadIdx.x;
    const int lane = tid & 63;
    const int wv = tid >> 6;
    const int n = blockIdx.z;
    const int ty0 = blockIdx.y*8, tx0 = blockIdx.x*16;
    const int lx = lane & 15;
    const int lg = lane >> 4;
    const int gx_out = tx0 + lx;
    const int gp = tid >> 2;
    const int gg = tid & 3;

    const ushort* xn = xbf + (size_t)n*HW*64;
    const float* offn = off + (size_t)n*18*HW;

    ffrag acc[4][2];
#pragma unroll
    for (int mt = 0; mt < 4; ++mt)
#pragma unroll
        for (int q = 0; q < 2; ++q) acc[mt][q] = (ffrag){0.f,0.f,0.f,0.f};

    int buf = 0;
    for (int tap = 0; tap < 9; ++tap){
        const int ti = tap/3, tj = tap%3;
#pragma unroll
        for (int pass = 0; pass < 2; ++pass){
            const int p = pass*64 + gp;
            const int py_ = ty0 + (p >> 4), px_ = tx0 + (p & 15);
            float dy = offn[(size_t)(2*tap)*HW + py_*WW + px_];
            float dx = offn[(size_t)(2*tap+1)*HW + py_*WW + px_];
            float sy = (float)(py_ + ti - 1) + dy;
            float sx = (float)(px_ + tj - 1) + dx;
            float y0f = floorf(sy), x0f = floorf(sx);
            float wy1 = sy - y0f, wx1 = sx - x0f;
            float wy0 = 1.f - wy1, wx0 = 1.f - wx1;
            int y0 = (int)y0f, x0 = (int)x0f;
            int y1 = y0+1, x1 = x0+1;
            float vy0 = (y0 >= 0 && y0 < HH) ? 1.f : 0.f;
            float vy1 = (y1 >= 0 && y1 < HH) ? 1.f : 0.f;
            float vx0 = (x0 >= 0 && x0 < WW) ? 1.f : 0.f;
            float vx1 = (x1 >= 0 && x1 < WW) ? 1.f : 0.f;
            float w00 = wy0*wx0*vy0*vx0, w01 = wy0*wx1*vy0*vx1;
            float w10 = wy1*wx0*vy1*vx0, w11 = wy1*wx1*vy1*vx1;
            int yc0 = min(max(y0,0),HH-1), yc1 = min(max(y1,0),HH-1);
            int xc0 = min(max(x0,0),WW-1), xc1 = min(max(x1,0),WW-1);
            int b00 = (yc0*WW + xc0)*64, b01 = (yc0*WW + xc1)*64;
            int b10 = (yc1*WW + xc0)*64, b11 = (yc1*WW + xc1)*64;
#pragma unroll
            for (int cb = 0; cb < 2; ++cb){
                const int ch = cb*32 + gg*8;
                uint4 c00 = *(const uint4*)(xn + b00 + ch);
                uint4 c01 = *(const uint4*)(xn + b01 + ch);
                uint4 c10 = *(const uint4*)(xn + b10 + ch);
                uint4 c11 = *(const uint4*)(xn + b11 + ch);
                const ushort* e00 = (const ushort*)&c00;
                const ushort* e01 = (const ushort*)&c01;
                const ushort* e10 = (const ushort*)&c10;
                const ushort* e11 = (const ushort*)&c11;
                ushort pk[8];
#pragma unroll
                for (int j = 0; j < 8; ++j){
                    float s = bf2f(e00[j])*w00 + bf2f(e01[j])*w01
                            + bf2f(e10[j])*w10 + bf2f(e11[j])*w11;
                    pk[j] = f2bf(s);
                }
                const int sl = (cb*4 + gg) ^ (p & 7);
                *(uint4*)&sS[buf][p*64 + sl*8] = *(uint4*)pk;
            }
        }
        __syncthreads();
#pragma unroll
        for (int cb = 0; cb < 2; ++cb){
            const bfrag* wbase = (const bfrag*)wf + ((size_t)(cb*9 + tap)*4)*64 + lane;
            bfrag a[4];
#pragma unroll
            for (int mt = 0; mt < 4; ++mt) a[mt] = wbase[mt*64];
#pragma unroll
            for (int q = 0; q < 2; ++q){
                const int p = (wv*2 + q)*16 + lx;
                const int sl = (cb*4 + lg) ^ (p & 7);
                bfrag b = *(const bfrag*)&sS[buf][p*64 + sl*8];
#pragma unroll
                for (int mt = 0; mt < 4; ++mt)
                    acc[mt][q] = __builtin_amdgcn_mfma_f32_16x16x32_bf16(a[mt], b, acc[mt][q], 0, 0, 0);
            }
        }
        buf ^= 1;
    }
#pragma unroll
    for (int mt = 0; mt < 4; ++mt){
        const int co0 = mt*16 + lg*4;
#pragma unroll
        for (int q = 0; q < 2; ++q){
            const int gy = ty0 + wv*2 + q;
            float r[4];
            ushort pk[4];
#pragma unroll
            for (int j = 0; j < 4; ++j){
                r[j] = fmaxf(acc[mt][q][j] + bias[co0+j], 0.f);
                pk[j] = f2bf(r[j]);
            }
#pragma unroll
            for (int j = 0; j < 4; ++j)
                xo[((size_t)(n*64 + co0 + j))*HW + (size_t)gy*WW + gx_out] = r[j];
            *(uint2*)(xobf + ((size_t)n*HW + gy*WW + gx_out)*64 + co0) = *(uint2*)pk;
        }
    }
}

extern "C" void kernel_launch(void* const* d_in, const int* in_sizes, int n_in,
                              void* d_out, int out_size, void* d_ws, size_t ws_size,
                              hipStream_t stream)
{
    const float* x      = (const float*)d_in[0];
    const float* ref_x  = (const float*)d_in[1];
    const float* ref_w  = (const float*)d_in[2];
    const float* ref_b  = (const float*)d_in[3];
    const float* off_w1 = (const float*)d_in[4];
    const float* off_b1 = (const float*)d_in[5];
    const float* ca1_w1 = (const float*)d_in[6];
    const float* ca1_b1 = (const float*)d_in[7];
    const float* ca1_w2 = (const float*)d_in[8];
    const float* ca1_b2 = (const float*)d_in[9];
    const float* off_w2 = (const float*)d_in[10];
    const float* off_b2 = (const float*)d_in[11];
    const float* ca2_w1 = (const float*)d_in[12];
    const float* ca2_b1 = (const float*)d_in[13];
    const float* ca2_w2 = (const float*)d_in[14];
    const float* ca2_b2 = (const float*)d_in[15];
    const float* off_w3 = (const float*)d_in[16];
    const float* off_b3 = (const float*)d_in[17];
    const float* dcn_w  = (const float*)d_in[18];
    const float* dcn_b  = (const float*)d_in[19];
    const float* rgb_w  = (const float*)d_in[20];
    const float* rgb_b  = (const float*)d_in[21];

    float* out = (float*)d_out;
    const size_t XO  = (size_t)8 * 64 * HW;
    const size_t RGB = (size_t)8 * 3 * HW;
    const size_t OFF = (size_t)8 * 18 * HW;
    float* xo_out   = out;
    float* rgb_out  = out + XO;
    float* mask_out = out + XO + RGB;
    float* off_out  = out + XO + RGB + OFF;

    const size_t NPX = (size_t)8 * HW;
    ushort* ws16  = (ushort*)d_ws;
    ushort* x_bf  = ws16;                       // NPX*64
    ushort* bufP  = x_bf + NPX*64;              // ref_f, later t2
    ushort* bufQ  = bufP + NPX*64;              // t1, later xo_bf
    ushort* rc_bf = bufQ + NPX*64;              // NPX*32
    ushort* wf_ref = rc_bf + NPX*32;            // 18432
    ushort* wf_1   = wf_ref + 18432;            // 73728
    ushort* wf_2   = wf_1 + 73728;              // 36864
    ushort* wf_3   = wf_2 + 36864;              // 18432
    ushort* wf_d   = wf_3 + 18432;              // 36864
    ushort* wf_r   = wf_d + 36864;              // 9216
    float*  part1  = (float*)(wf_r + 9216);     // 8*144*64
    float*  part2  = part1 + 73728;
    float*  s1     = part2 + 73728;
    float*  s2     = s1 + 512;

    dim3 pg(144, 8, 2), cg(12, 12, 8), dg(12, 24, 8);

    k_prep<<<pg, 256, 0, stream>>>(x, ref_x, x_bf, rc_bf);
    k_wfrag_all<<<dim3(288, 6), 256, 0, stream>>>(
        ref_w, off_w1, off_w2, off_w3, dcn_w, rgb_w,
        wf_ref, wf_1, wf_2, wf_3, wf_d, wf_r);

    // ref: 32ch(12 real) -> 64, relu, bf16 out
    kc_ref<<<cg, 256, 0, stream>>>(rc_bf, wf_ref, ref_b, bufP);
    // off1: concat(x, ref_f) 128 -> 64, relu, bf16 out + GAP partials
    kc_off1<<<cg, 256, 0, stream>>>(x_bf, bufP, wf_1, off_b1, bufQ, part1);
    k_cafc<<<8, 64, 0, stream>>>(part1, ca1_w1, ca1_b1, ca1_w2, ca1_b2, s1);
    // off2: (t1*s1) 64 -> 64, relu, bf16 out + GAP partials
    kc_off2<<<cg, 256, 0, stream>>>(bufQ, wf_2, off_b2, s1, bufP, part2);
    k_cafc<<<8, 64, 0, stream>>>(part2, ca2_w1, ca2_b1, ca2_w2, ca2_b2, s2);
    // off3: (t2*s2) 64 -> 18, f32 NCHW dual (offset + mask)
    kc_off3<<<cg, 256, 0, stream>>>(bufP, wf_3, off_b3, s2, off_out, mask_out);
    // deformable conv -> xo (f32 NCHW) + xo_bf (NHWC)
    k_dcnm<<<dg, 256, 0, stream>>>(x_bf, off_out, wf_d, dcn_b, xo_out, bufQ);
    // rgb: xo 64 -> 3, f32 NCHW
    kc_rgb<<<cg, 256, 0, stream>>>(bufQ, wf_r, rgb_b, rgb_out);
}

// Round 19
// 317.231 us; speedup vs baseline: 1.4008x; 1.0091x over previous
//
#include <hip/hip_runtime.h>
#include <hip/hip_bf16.h>
#include <math.h>

#define HH 192
#define WW 192
#define HW (192*192)

typedef __attribute__((ext_vector_type(8))) short bfrag;   // 8 x bf16 (4 VGPR)
typedef __attribute__((ext_vector_type(4))) float ffrag;   // 4 x f32 acc

__device__ __forceinline__ float bf2f(ushort u){
    union { unsigned int i; float f; } c; c.i = ((unsigned int)u) << 16; return c.f;
}
__device__ __forceinline__ ushort f2bf(float f){
    __hip_bfloat16 h = __float2bfloat16(f);
    return *reinterpret_cast<ushort*>(&h);
}

// ---------------- prep: z=0 NCHW->NHWC bf16 (64ch); z=1 ref_x flip-augment (32ch) ----------------
__global__ __launch_bounds__(256)
void k_prep(const float* __restrict__ x, const float* __restrict__ rx,
            ushort* __restrict__ xbf, ushort* __restrict__ rcbf){
    const int n = blockIdx.y;
    const int tid = threadIdx.x;
    if (blockIdx.z == 0){
        __shared__ ushort sT[256*64];
        const int px0 = blockIdx.x * 256;
        for (int c = 0; c < 64; ++c){
            float v = x[((size_t)(n*64 + c))*HW + px0 + tid];
            int slot = (((c >> 3) ^ (tid & 7)) << 3) + (c & 7);
            sT[tid*64 + slot] = f2bf(v);
        }
        __syncthreads();
        for (int r = 0; r < 8; ++r){
            int u = r*256 + tid;
            int pl = u >> 3, g = u & 7;
            uint4 v = *(const uint4*)&sT[pl*64 + ((g ^ (pl & 7)) << 3)];
            *(uint4*)(xbf + ((size_t)n*HW + px0 + pl)*64 + g*8) = v;
        }
    } else {
        const int px = blockIdx.x*256 + tid;
        const int y = px / WW, xx = px - y*WW;
        ushort v[32];
#pragma unroll
        for (int m = 0; m < 4; ++m){
            int ry = (m & 1) ? (HH-1-y) : y;
            int rxp = (m & 2) ? (WW-1-xx) : xx;
#pragma unroll
            for (int c = 0; c < 3; ++c)
                v[m*3+c] = f2bf(rx[((size_t)(n*3+c))*HW + ry*WW + rxp]);
        }
#pragma unroll
        for (int j = 12; j < 32; ++j) v[j] = 0;
#pragma unroll
        for (int k = 0; k < 4; ++k)
            *(uint4*)(rcbf + ((size_t)n*HW + px)*32 + k*8) = *(uint4*)&v[k*8];
    }
}

// ---------------- all weights -> MFMA A-fragment order, one launch ----------------
__global__ void k_wfrag_all(const float* __restrict__ w0, const float* __restrict__ w1,
                            const float* __restrict__ w2, const float* __restrict__ w3,
                            const float* __restrict__ w4, const float* __restrict__ w5,
                            ushort* __restrict__ f0, ushort* __restrict__ f1,
                            ushort* __restrict__ f2, ushort* __restrict__ f3,
                            ushort* __restrict__ f4, ushort* __restrict__ f5){
    const float* w; ushort* wf; int cin_real, ncb, cout_real, mt;
    switch (blockIdx.y){
        case 0: w=w0; wf=f0; cin_real=12;  ncb=1; cout_real=64; mt=4; break;
        case 1: w=w1; wf=f1; cin_real=128; ncb=4; cout_real=64; mt=4; break;
        case 2: w=w2; wf=f2; cin_real=64;  ncb=2; cout_real=64; mt=4; break;
        case 3: w=w3; wf=f3; cin_real=64;  ncb=2; cout_real=18; mt=2; break;
        case 4: w=w4; wf=f4; cin_real=64;  ncb=2; cout_real=64; mt=4; break;
        default:w=w5; wf=f5; cin_real=64;  ncb=2; cout_real=3;  mt=1; break;
    }
    int idx = blockIdx.x*256 + threadIdx.x;
    int total = ncb*9*mt*512;
    if (idx >= total) return;
    int e = idx & 7;
    int lane = (idx >> 3) & 63;
    int rest = idx >> 9;
    int mtl = rest % mt;
    int tap = (rest / mt) % 9;
    int cb  = rest / (mt*9);
    int cout = mtl*16 + (lane & 15);
    int cin  = cb*32 + ((lane >> 4) << 3) + e;
    float v = 0.f;
    if (cout < cout_real && cin < cin_real)
        v = w[((size_t)cout*cin_real + cin)*9 + tap];
    wf[idx] = f2bf(v);
}

// ---------------- implicit-GEMM 3x3 conv body ----------------
// OM&1 epilogue: stage output tile in LDS (two 8-row passes, 16B-granule XOR swizzle),
// stream out as full 128B/pixel lines -> no write-allocate FETCH inflation.
template<int NCB, int MT, bool SCALE, bool CONCAT, bool RELU, int OM, bool GAPP>
__device__ __forceinline__
void conv_body(const ushort* __restrict__ in0, const ushort* __restrict__ in1,
               const ushort* __restrict__ wf, const float* __restrict__ bias,
               const float* __restrict__ scale,
               ushort* __restrict__ obf, float* __restrict__ of0, float* __restrict__ of1,
               float* __restrict__ part, int cout_real)
{
    __shared__ ushort sXt[18*18*32];
    __shared__ float sG[4][4][16];
    __shared__ ushort sOut[(OM & 1) ? 8*16*64 : 1];   // 16KB half-tile out-stage
    const int tid = threadIdx.x;
    const int lane = tid & 63;
    const int wv = tid >> 6;
    const int n = blockIdx.z;
    const int ty0 = blockIdx.y*16, tx0 = blockIdx.x*16;
    const int lx = lane & 15;
    const int lg = lane >> 4;

    ffrag acc[MT][4];
#pragma unroll
    for (int mt = 0; mt < MT; ++mt)
#pragma unroll
        for (int q = 0; q < 4; ++q) acc[mt][q] = (ffrag){0.f,0.f,0.f,0.f};

    for (int cb = 0; cb < NCB; ++cb){
        __syncthreads();
        for (int u = tid; u < 1296; u += 256){
            int yy = u / 72; int rr = u - yy*72; int xx = rr >> 2; int g = rr & 3;
            int gy = ty0 - 1 + yy, gx = tx0 - 1 + xx;
            uint4 val = make_uint4(0,0,0,0);
            if (gy >= 0 && gy < HH && gx >= 0 && gx < WW){
                const ushort* src; int ch; int stride;
                if constexpr (CONCAT){
                    src = (cb < 2) ? in0 : in1;
                    ch = (cb & 1)*32 + g*8;
                    stride = 64;
                } else {
                    src = in0; ch = cb*32 + g*8; stride = NCB*32;
                }
                val = *(const uint4*)(src + ((size_t)n*HW + gy*WW + gx)*stride + ch);
                if constexpr (SCALE){
                    ushort* e = (ushort*)&val;
                    int cb8 = cb*32 + g*8;
#pragma unroll
                    for (int j = 0; j < 8; ++j)
                        e[j] = f2bf(bf2f(e[j]) * scale[n*64 + cb8 + j]);
                }
            }
            *(uint4*)&sXt[((yy*18 + xx)*4 + (g ^ ((xx >> 1) & 3)))*8] = val;
        }
        __syncthreads();

        const bfrag* wbase = (const bfrag*)wf + (size_t)cb*9*MT*64 + lane;
        bfrag a[MT];
#pragma unroll
        for (int mt = 0; mt < MT; ++mt) a[mt] = wbase[mt*64];

#pragma unroll
        for (int tap = 0; tap < 9; ++tap){
            const int ky = tap / 3, kx = tap % 3;
            bfrag an[MT];
            if (tap < 8){
#pragma unroll
                for (int mt = 0; mt < MT; ++mt) an[mt] = wbase[(tap+1)*MT*64 + mt*64];
            }
#pragma unroll
            for (int q = 0; q < 4; ++q){
                const int yl = wv*4 + q + ky;
                const int xl = lx + kx;
                bfrag b = *(const bfrag*)&sXt[((yl*18 + xl)*4 + (lg ^ ((xl >> 1) & 3)))*8];
#pragma unroll
                for (int mt = 0; mt < MT; ++mt)
                    acc[mt][q] = __builtin_amdgcn_mfma_f32_16x16x32_bf16(a[mt], b, acc[mt][q], 0, 0, 0);
            }
            if (tap < 8){
#pragma unroll
                for (int mt = 0; mt < MT; ++mt) a[mt] = an[mt];
            }
        }
    }
    const int gx = tx0 + lx;
    float psum[MT][4];
    if constexpr (GAPP){
#pragma unroll
        for (int mt = 0; mt < MT; ++mt)
#pragma unroll
            for (int j = 0; j < 4; ++j) psum[mt][j] = 0.f;
    }

    if constexpr (OM & 1){
#pragma unroll
        for (int pass = 0; pass < 2; ++pass){
            if ((wv >> 1) == pass){
#pragma unroll
                for (int mt = 0; mt < MT; ++mt){
                    const int co0 = mt*16 + lg*4;
                    const int t = mt*2 + (lg >> 1);
                    const int h = lg & 1;
#pragma unroll
                    for (int q = 0; q < 4; ++q){
                        const int py_loc = (wv*4 + q) & 7;
                        float r[4];
                        ushort pk[4];
#pragma unroll
                        for (int j = 0; j < 4; ++j){
                            float bv = (co0 + j < cout_real) ? bias[co0 + j] : 0.f;
                            float v = acc[mt][q][j] + bv;
                            if (RELU) v = fmaxf(v, 0.f);
                            r[j] = v;
                            pk[j] = f2bf(v);
                        }
                        if constexpr (GAPP){
#pragma unroll
                            for (int j = 0; j < 4; ++j) psum[mt][j] += r[j];
                        }
                        *(uint2*)&sOut[(py_loc*16 + lx)*64 + ((t ^ (lx & 7)) << 3) + h*4] = *(uint2*)pk;
                    }
                }
            }
            __syncthreads();
#pragma unroll
            for (int it = 0; it < 4; ++it){
                int u = it*256 + tid;
                int p = u >> 3, t = u & 7;
                int py = p >> 4, px = p & 15;
                uint4 v = *(const uint4*)&sOut[(py*16 + px)*64 + ((t ^ (px & 7)) << 3)];
                *(uint4*)(obf + ((size_t)n*HW + (size_t)(ty0 + pass*8 + py)*WW + tx0 + px)*64 + t*8) = v;
            }
            __syncthreads();
        }
    } else {
#pragma unroll
        for (int mt = 0; mt < MT; ++mt){
            const int co0 = mt*16 + lg*4;
#pragma unroll
            for (int q = 0; q < 4; ++q){
                const int gy = ty0 + wv*4 + q;
                float r[4];
#pragma unroll
                for (int j = 0; j < 4; ++j){
                    float bv = (co0 + j < cout_real) ? bias[co0 + j] : 0.f;
                    float v = acc[mt][q][j] + bv;
                    if (RELU) v = fmaxf(v, 0.f);
                    r[j] = v;
                }
                if constexpr (GAPP){
#pragma unroll
                    for (int j = 0; j < 4; ++j) psum[mt][j] += r[j];
                }
#pragma unroll
                for (int j = 0; j < 4; ++j){
                    int c = co0 + j;
                    if (c < cout_real){
                        size_t o = ((size_t)(n*cout_real + c))*HW + (size_t)gy*WW + gx;
                        of0[o] = r[j];
                        if (of1) of1[o] = r[j];
                    }
                }
            }
        }
    }

    if constexpr (GAPP){
#pragma unroll
        for (int mt = 0; mt < MT; ++mt)
#pragma unroll
            for (int j = 0; j < 4; ++j){
                float v = psum[mt][j];
#pragma unroll
                for (int d = 1; d < 16; d <<= 1) v += __shfl_xor(v, d, 64);
                if (lx == 0) sG[wv][lg][mt*4 + j] = v;
            }
        __syncthreads();
        if (tid < 64){
            int mt = tid >> 4, lgc = (tid >> 2) & 3, j = tid & 3;
            float s = sG[0][lgc][mt*4+j] + sG[1][lgc][mt*4+j]
                    + sG[2][lgc][mt*4+j] + sG[3][lgc][mt*4+j];
            part[(((size_t)n*144) + blockIdx.y*12 + blockIdx.x)*64 + tid] = s;
        }
    }
}

// -------- uniquely-named conv kernels --------
__global__ __launch_bounds__(256, 2)
void kc_ref(const ushort* __restrict__ in0, const ushort* __restrict__ wf,
            const float* __restrict__ bias, ushort* __restrict__ obf){
    conv_body<1,4,false,false,true,1,false>(in0, nullptr, wf, bias, nullptr, obf, nullptr, nullptr, nullptr, 64);
}
__global__ __launch_bounds__(256, 2)
void kc_off1(const ushort* __restrict__ in0, const ushort* __restrict__ in1,
             const ushort* __restrict__ wf, const float* __restrict__ bias,
             ushort* __restrict__ obf, float* __restrict__ part){
    conv_body<4,4,false,true,true,1,true>(in0, in1, wf, bias, nullptr, obf, nullptr, nullptr, part, 64);
}
__global__ __launch_bounds__(256, 2)
void kc_off2(const ushort* __restrict__ in0, const ushort* __restrict__ wf,
             const float* __restrict__ bias, const float* __restrict__ scale,
             ushort* __restrict__ obf, float* __restrict__ part){
    conv_body<2,4,true,false,true,1,true>(in0, nullptr, wf, bias, scale, obf, nullptr, nullptr, part, 64);
}
__global__ __launch_bounds__(256, 2)
void kc_off3(const ushort* __restrict__ in0, const ushort* __restrict__ wf,
             const float* __restrict__ bias, const float* __restrict__ scale,
             float* __restrict__ of0, float* __restrict__ of1){
    conv_body<2,2,true,false,false,2,false>(in0, nullptr, wf, bias, scale, nullptr, of0, of1, nullptr, 18);
}
__global__ __launch_bounds__(256, 2)
void kc_rgb(const ushort* __restrict__ in0, const ushort* __restrict__ wf,
            const float* __restrict__ bias, float* __restrict__ of0){
    conv_body<2,1,false,false,false,2,false>(in0, nullptr, wf, bias, nullptr, nullptr, of0, nullptr, nullptr, 3);
}

// ---------------- channel-attention FC ----------------
__global__ void k_cafc(const float* __restrict__ part, const float* __restrict__ w1,
                       const float* __restrict__ b1, const float* __restrict__ w2,
                       const float* __restrict__ b2, float* __restrict__ s)
{
    int n = blockIdx.x;
    int c = threadIdx.x;  // 64
    __shared__ float y[64], z[4];
    float acc = 0.f;
    for (int b = 0; b < 144; ++b) acc += part[((size_t)n*144 + b)*64 + c];
    y[c] = acc * (1.f/(float)HW);
    __syncthreads();
    if (c < 4){
        float a = b1[c];
        for (int i = 0; i < 64; ++i) a = fmaf(w1[c*64+i], y[i], a);
        z[c] = fmaxf(a, 0.f);
    }
    __syncthreads();
    float a = b2[c];
#pragma unroll
    for (int q = 0; q < 4; ++q) a = fmaf(w2[c*4+q], z[q], a);
    s[n*64+c] = 1.f/(1.f+expf(-a));
}

// ---------------- deformable conv: 8x16 tile, dbuf LDS, pixel-grouped gather -> MFMA ----------------
// Round-13 structure + full-line xobf epilogue: after the tap loop, sS[0] (dead) stages the
// 128px x 64ch bf16 output tile (same XOR swizzle), then streamed as full 128B/pixel lines.
__global__ __launch_bounds__(256, 2)
void k_dcnm(const ushort* __restrict__ xbf, const float* __restrict__ off,
            const ushort* __restrict__ wf, const float* __restrict__ bias,
            float* __restrict__ xo, ushort* __restrict__ xobf)
{
    __shared__ ushort sS[2][128*64];   // [buf][pixel*64 + slot*8 + e], slot = slice ^ (p&7); 2x16KB
    const int tid = threadIdx.x;
    const int lane = tid & 63;
    const int wv = tid >> 6;
    const int n = blockIdx.z;
    const int ty0 = blockIdx.y*8, tx0 = blockIdx.x*16;
    const int lx = lane & 15;
    const int lg = lane >> 4;
    const int gx_out = tx0 + lx;
    const int gp = tid >> 2;
    const int gg = tid & 3;

    const ushort* xn = xbf + (size_t)n*HW*64;
    const float* offn = off + (size_t)n*18*HW;

    ffrag acc[4][2];
#pragma unroll
    for (int mt = 0; mt < 4; ++mt)
#pragma unroll
        for (int q = 0; q < 2; ++q) acc[mt][q] = (ffrag){0.f,0.f,0.f,0.f};

    int buf = 0;
    for (int tap = 0; tap < 9; ++tap){
        const int ti = tap/3, tj = tap%3;
#pragma unroll
        for (int pass = 0; pass < 2; ++pass){
            const int p = pass*64 + gp;
            const int py_ = ty0 + (p >> 4), px_ = tx0 + (p & 15);
            float dy = offn[(size_t)(2*tap)*HW + py_*WW + px_];
            float dx = offn[(size_t)(2*tap+1)*HW + py_*WW + px_];
            float sy = (float)(py_ + ti - 1) + dy;
            float sx = (float)(px_ + tj - 1) + dx;
            float y0f = floorf(sy), x0f = floorf(sx);
            float wy1 = sy - y0f, wx1 = sx - x0f;
            float wy0 = 1.f - wy1, wx0 = 1.f - wx1;
            int y0 = (int)y0f, x0 = (int)x0f;
            int y1 = y0+1, x1 = x0+1;
            float vy0 = (y0 >= 0 && y0 < HH) ? 1.f : 0.f;
            float vy1 = (y1 >= 0 && y1 < HH) ? 1.f : 0.f;
            float vx0 = (x0 >= 0 && x0 < WW) ? 1.f : 0.f;
            float vx1 = (x1 >= 0 && x1 < WW) ? 1.f : 0.f;
            float w00 = wy0*wx0*vy0*vx0, w01 = wy0*wx1*vy0*vx1;
            float w10 = wy1*wx0*vy1*vx0, w11 = wy1*wx1*vy1*vx1;
            int yc0 = min(max(y0,0),HH-1), yc1 = min(max(y1,0),HH-1);
            int xc0 = min(max(x0,0),WW-1), xc1 = min(max(x1,0),WW-1);
            int b00 = (yc0*WW + xc0)*64, b01 = (yc0*WW + xc1)*64;
            int b10 = (yc1*WW + xc0)*64, b11 = (yc1*WW + xc1)*64;
#pragma unroll
            for (int cb = 0; cb < 2; ++cb){
                const int ch = cb*32 + gg*8;
                uint4 c00 = *(const uint4*)(xn + b00 + ch);
                uint4 c01 = *(const uint4*)(xn + b01 + ch);
                uint4 c10 = *(const uint4*)(xn + b10 + ch);
                uint4 c11 = *(const uint4*)(xn + b11 + ch);
                const ushort* e00 = (const ushort*)&c00;
                const ushort* e01 = (const ushort*)&c01;
                const ushort* e10 = (const ushort*)&c10;
                const ushort* e11 = (const ushort*)&c11;
                ushort pk[8];
#pragma unroll
                for (int j = 0; j < 8; ++j){
                    float s = bf2f(e00[j])*w00 + bf2f(e01[j])*w01
                            + bf2f(e10[j])*w10 + bf2f(e11[j])*w11;
                    pk[j] = f2bf(s);
                }
                const int sl = (cb*4 + gg) ^ (p & 7);
                *(uint4*)&sS[buf][p*64 + sl*8] = *(uint4*)pk;
            }
        }
        __syncthreads();
#pragma unroll
        for (int cb = 0; cb < 2; ++cb){
            const bfrag* wbase = (const bfrag*)wf + ((size_t)(cb*9 + tap)*4)*64 + lane;
            bfrag a[4];
#pragma unroll
            for (int mt = 0; mt < 4; ++mt) a[mt] = wbase[mt*64];
#pragma unroll
            for (int q = 0; q < 2; ++q){
                const int p = (wv*2 + q)*16 + lx;
                const int sl = (cb*4 + lg) ^ (p & 7);
                bfrag b = *(const bfrag*)&sS[buf][p*64 + sl*8];
#pragma unroll
                for (int mt = 0; mt < 4; ++mt)
                    acc[mt][q] = __builtin_amdgcn_mfma_f32_16x16x32_bf16(a[mt], b, acc[mt][q], 0, 0, 0);
            }
        }
        buf ^= 1;
    }
    // epilogue: xo f32 NCHW direct; xobf staged through sS[0] for full-line writes
    __syncthreads();   // all waves done with last tap's sS reads before reuse
#pragma unroll
    for (int mt = 0; mt < 4; ++mt){
        const int co0 = mt*16 + lg*4;
        const int t = mt*2 + (lg >> 1);
        const int h = lg & 1;
#pragma unroll
        for (int q = 0; q < 2; ++q){
            const int gy = ty0 + wv*2 + q;
            const int p = (wv*2 + q)*16 + lx;
            float r[4];
            ushort pk[4];
#pragma unroll
            for (int j = 0; j < 4; ++j){
                r[j] = fmaxf(acc[mt][q][j] + bias[co0+j], 0.f);
                pk[j] = f2bf(r[j]);
            }
#pragma unroll
            for (int j = 0; j < 4; ++j)
                xo[((size_t)(n*64 + co0 + j))*HW + (size_t)gy*WW + gx_out] = r[j];
            *(uint2*)&sS[0][p*64 + ((t ^ (lx & 7)) << 3) + h*4] = *(uint2*)pk;
        }
    }
    __syncthreads();
#pragma unroll
    for (int it = 0; it < 4; ++it){
        int u = it*256 + tid;
        int p = u >> 3, t = u & 7;
        int py = p >> 4, px = p & 15;
        uint4 v = *(const uint4*)&sS[0][p*64 + ((t ^ (px & 7)) << 3)];
        *(uint4*)(xobf + ((size_t)n*HW + (size_t)(ty0 + py)*WW + tx0 + px)*64 + t*8) = v;
    }
}

extern "C" void kernel_launch(void* const* d_in, const int* in_sizes, int n_in,
                              void* d_out, int out_size, void* d_ws, size_t ws_size,
                              hipStream_t stream)
{
    const float* x      = (const float*)d_in[0];
    const float* ref_x  = (const float*)d_in[1];
    const float* ref_w  = (const float*)d_in[2];
    const float* ref_b  = (const float*)d_in[3];
    const float* off_w1 = (const float*)d_in[4];
    const float* off_b1 = (const float*)d_in[5];
    const float* ca1_w1 = (const float*)d_in[6];
    const float* ca1_b1 = (const float*)d_in[7];
    const float* ca1_w2 = (const float*)d_in[8];
    const float* ca1_b2 = (const float*)d_in[9];
    const float* off_w2 = (const float*)d_in[10];
    const float* off_b2 = (const float*)d_in[11];
    const float* ca2_w1 = (const float*)d_in[12];
    const float* ca2_b1 = (const float*)d_in[13];
    const float* ca2_w2 = (const float*)d_in[14];
    const float* ca2_b2 = (const float*)d_in[15];
    const float* off_w3 = (const float*)d_in[16];
    const float* off_b3 = (const float*)d_in[17];
    const float* dcn_w  = (const float*)d_in[18];
    const float* dcn_b  = (const float*)d_in[19];
    const float* rgb_w  = (const float*)d_in[20];
    const float* rgb_b  = (const float*)d_in[21];

    float* out = (float*)d_out;
    const size_t XO  = (size_t)8 * 64 * HW;
    const size_t RGB = (size_t)8 * 3 * HW;
    const size_t OFF = (size_t)8 * 18 * HW;
    float* xo_out   = out;
    float* rgb_out  = out + XO;
    float* mask_out = out + XO + RGB;
    float* off_out  = out + XO + RGB + OFF;

    const size_t NPX = (size_t)8 * HW;
    ushort* ws16  = (ushort*)d_ws;
    ushort* x_bf  = ws16;                       // NPX*64
    ushort* bufP  = x_bf + NPX*64;              // ref_f, later t2
    ushort* bufQ  = bufP + NPX*64;              // t1, later xo_bf
    ushort* rc_bf = bufQ + NPX*64;              // NPX*32
    ushort* wf_ref = rc_bf + NPX*32;            // 18432
    ushort* wf_1   = wf_ref + 18432;            // 73728
    ushort* wf_2   = wf_1 + 73728;              // 36864
    ushort* wf_3   = wf_2 + 36864;              // 18432
    ushort* wf_d   = wf_3 + 18432;              // 36864
    ushort* wf_r   = wf_d + 36864;              // 9216
    float*  part1  = (float*)(wf_r + 9216);     // 8*144*64
    float*  part2  = part1 + 73728;
    float*  s1     = part2 + 73728;
    float*  s2     = s1 + 512;

    dim3 pg(144, 8, 2), cg(12, 12, 8), dg(12, 24, 8);

    k_prep<<<pg, 256, 0, stream>>>(x, ref_x, x_bf, rc_bf);
    k_wfrag_all<<<dim3(288, 6), 256, 0, stream>>>(
        ref_w, off_w1, off_w2, off_w3, dcn_w, rgb_w,
        wf_ref, wf_1, wf_2, wf_3, wf_d, wf_r);

    // ref: 32ch(12 real) -> 64, relu, bf16 out
    kc_ref<<<cg, 256, 0, stream>>>(rc_bf, wf_ref, ref_b, bufP);
    // off1: concat(x, ref_f) 128 -> 64, relu, bf16 out + GAP partials
    kc_off1<<<cg, 256, 0, stream>>>(x_bf, bufP, wf_1, off_b1, bufQ, part1);
    k_cafc<<<8, 64, 0, stream>>>(part1, ca1_w1, ca1_b1, ca1_w2, ca1_b2, s1);
    // off2: (t1*s1) 64 -> 64, relu, bf16 out + GAP partials
    kc_off2<<<cg, 256, 0, stream>>>(bufQ, wf_2, off_b2, s1, bufP, part2);
    k_cafc<<<8, 64, 0, stream>>>(part2, ca2_w1, ca2_b1, ca2_w2, ca2_b2, s2);
    // off3: (t2*s2) 64 -> 18, f32 NCHW dual (offset + mask)
    kc_off3<<<cg, 256, 0, stream>>>(bufP, wf_3, off_b3, s2, off_out, mask_out);
    // deformable conv -> xo (f32 NCHW) + xo_bf (NHWC)
    k_dcnm<<<dg, 256, 0, stream>>>(x_bf, off_out, wf_d, dcn_b, xo_out, bufQ);
    // rgb: xo 64 -> 3, f32 NCHW
    kc_rgb<<<cg, 256, 0, stream>>>(bufQ, wf_r, rgb_b, rgb_out);
}